// Round 7
// baseline (95.301 us; speedup 1.0000x reference)
//
#include <hip/hip_runtime.h>
#include <math.h>

#define NSPK 1024
#define NUTT 32
#define DIM  128
#define NROWS (NSPK * NUTT)
#define EPS 1e-8f
#define LOG2E 1.44269504f

typedef __attribute__((ext_vector_type(8))) short short8;
typedef __attribute__((ext_vector_type(4))) float floatx4;

__device__ inline unsigned short f2bf(float f) {  // RNE fp32 -> bf16
  union { float f; unsigned u; } v; v.f = f;
  unsigned r = v.u + 0x7fffu + ((v.u >> 16) & 1u);
  return (unsigned short)(r >> 16);
}

// async 16B global -> LDS (wave-uniform LDS base + lane*16)
__device__ __forceinline__ void gll16(const unsigned short* g, unsigned short* l) {
  __builtin_amdgcn_global_load_lds(
      (const __attribute__((address_space(1))) unsigned int*)g,
      (__attribute__((address_space(3))) unsigned int*)l, 16, 0, 0);
}

// ---------------------------------------------------------------------------
// k1: block b owns speakers {2b, 2b+1}. Writes bf16 unit centroids in CHUNKED
// layout centC[d>>3][spk][d&7] (16-B chunk = one lane's MFMA b-frag slice),
// plus per-row rs2/eol/olv. Block 0 zeroes d_out.
// ---------------------------------------------------------------------------
__global__ __launch_bounds__(256) void k1(const float* __restrict__ emb,
                                          const float* __restrict__ wp,
                                          const float* __restrict__ bp,
                                          unsigned short* __restrict__ centC,
                                          float* __restrict__ rs2g,
                                          float* __restrict__ eolg,
                                          float* __restrict__ olvg,
                                          float* __restrict__ out) {
  __shared__ __align__(16) float Sl[2 * 128];
  __shared__ float red[4];

  int b = blockIdx.x, t = threadIdx.x;
  float w = wp[0], bb = bp[0];
  float M = bb + fabsf(w);
  if (b == 0 && t == 0) out[0] = 0.f;

  int sp = t >> 7, d = t & 127;
  {
    const float* eb = emb + (size_t)(b * 2 + sp) * NUTT * DIM + d;
    float s = 0.f;
#pragma unroll
    for (int m = 0; m < NUTT; ++m) s += eb[m * DIM];
    Sl[sp * 128 + d] = s;
    float p = s * s;
#pragma unroll
    for (int mask = 1; mask < 64; mask <<= 1) p += __shfl_xor(p, mask, 64);
    if ((t & 63) == 0) red[t >> 6] = p;
  }
  __syncthreads();
  float ss0 = red[0] + red[1], ss1 = red[2] + red[3];

  {  // normalized bf16 centroid -> chunked layout
    float ss = sp ? ss1 : ss0;
    float s = Sl[sp * 128 + d];
    float cn = fmaxf(sqrtf(ss) * (1.0f / NUTT), EPS);
    centC[(size_t)(d >> 3) * (NSPK * 8) + (size_t)(b * 2 + sp) * 8 + (d & 7)] =
        f2bf(s / (NUTT * cn));
  }

  {  // per-row stats: 4 threads/row, 32 dims each (L1-hot re-read of emb)
    int row = t >> 2, sub = t & 3;
    int rsp = row >> 5;
    const float* er = emb + (size_t)(b * 64 + row) * DIM + sub * 32;
    const float* Srow = &Sl[rsp * 128 + sub * 32];
    float ee = 0.f, es = 0.f;
#pragma unroll
    for (int i = 0; i < 8; ++i) {
      float4 ev = *(const float4*)&er[i * 4];
      float4 sv = *(const float4*)&Srow[i * 4];
      ee += ev.x * ev.x + ev.y * ev.y + ev.z * ev.z + ev.w * ev.w;
      es += ev.x * sv.x + ev.y * sv.y + ev.z * sv.z + ev.w * sv.w;
    }
    ee += __shfl_xor(ee, 1, 64); es += __shfl_xor(es, 1, 64);
    ee += __shfl_xor(ee, 2, 64); es += __shfl_xor(es, 2, 64);
    if (sub == 0) {
      float ss = rsp ? ss1 : ss0;
      float en = fmaxf(sqrtf(ee), EPS);
      float dot_own = (es - ee) * (1.0f / (NUTT - 1));
      float ex2 = (ss - 2.f * es + ee) * (1.0f / ((NUTT - 1) * (NUTT - 1)));
      float cen = fmaxf(sqrtf(ex2), EPS);
      float ol = w * dot_own / (en * cen) + bb;
      int gr = b * 64 + row;
      olvg[gr] = ol;
      eolg[gr] = exp2f((ol - M) * LOG2E);
      rs2g[gr] = w * LOG2E / en;
    }
  }
}

// ---------------------------------------------------------------------------
// k2: 512 blocks x 256 thr (4 waves), 2 blocks/CU. Block = 64 rows x 1024
// cols, 16 passes x 64 cols. B staged via global_load_lds (async, 16B) into
// chunk-ordered LDS: chunk C = [region=consumer-wave][ks=stager-wave][lane]
// -> ALL ds accesses are lane-linear 16B (conflict-free). Double buffer,
// ONE barrier per pass. A-frags in regs; fixed-max exp2 LSE epilogue.
// ---------------------------------------------------------------------------
__global__ __launch_bounds__(256, 2) void k2(const float* __restrict__ emb,
                                             const unsigned short* __restrict__ centC,
                                             const float* __restrict__ rs2g,
                                             const float* __restrict__ eolg,
                                             const float* __restrict__ olvg,
                                             const float* __restrict__ wp,
                                             const float* __restrict__ bp,
                                             float* __restrict__ out) {
  __shared__ __align__(16) unsigned short A[64 * 136];   // 17.4 KB
  __shared__ __align__(16) unsigned short Bb[2][8192];   // 2 x 16 KB
  __shared__ __align__(16) float sPart[256];

  int b = blockIdx.x, t = threadIdx.x;
  int wid = t >> 6, lane = t & 63, lg = lane >> 4, lc = lane & 15;
  float w = wp[0], bb = bp[0];
  float M = bb + fabsf(w);
  float c2 = -fabsf(w) * LOG2E;

  // stage A: 64x128 fp32 -> bf16 LDS (coalesced float4)
#pragma unroll
  for (int i = 0; i < 8; ++i) {
    int idx4 = t + 256 * i;
    int r = idx4 >> 5, d4 = (idx4 & 31) << 2;
    float4 v = *(const float4*)(emb + (size_t)b * 8192 + (size_t)idx4 * 4);
    ushort4 bv;
    bv.x = f2bf(v.x); bv.y = f2bf(v.y); bv.z = f2bf(v.z); bv.w = f2bf(v.w);
    *(ushort4*)&A[r * 136 + d4] = bv;
  }

  // issue async stage of pass 0 into Bb[0]:
  // stager-wave `wid` provides k-slice rows (wid*4+lg)*8..+8 for all 4
  // consumer regions i; lane offset in LDS is implicit (+lane*16).
  const unsigned short* gbase = centC + ((size_t)(wid * 4 + lg) * NSPK + lc) * 8;
  {
#pragma unroll
    for (int i = 0; i < 4; ++i)
      gll16(gbase + (size_t)i * 16 * 8, &Bb[0][i * 2048 + wid * 512]);
  }

  __syncthreads();  // A ready + Bb[0] staged (vmcnt drained by barrier)

  short8 af[4][4];  // rows rt*16+lc, k = ks*32 + lg*8
#pragma unroll
  for (int rt = 0; rt < 4; ++rt)
#pragma unroll
    for (int ks = 0; ks < 4; ++ks)
      af[rt][ks] = *(const short8*)&A[(rt * 16 + lc) * 136 + ks * 32 + lg * 8];

  float rsL[16], eolL[16];  // rows rt*16 + lg*4 + reg
#pragma unroll
  for (int rt = 0; rt < 4; ++rt) {
    float4 r4 = *(const float4*)&rs2g[b * 64 + rt * 16 + lg * 4];
    float4 o4 = *(const float4*)&eolg[b * 64 + rt * 16 + lg * 4];
    rsL[rt * 4 + 0] = r4.x; rsL[rt * 4 + 1] = r4.y; rsL[rt * 4 + 2] = r4.z; rsL[rt * 4 + 3] = r4.w;
    eolL[rt * 4 + 0] = o4.x; eolL[rt * 4 + 1] = o4.y; eolL[rt * 4 + 2] = o4.z; eolL[rt * 4 + 3] = o4.w;
  }

  float sAcc[16];
#pragma unroll
  for (int j = 0; j < 16; ++j) sAcc[j] = 0.f;

  for (int p = 0; p < 16; ++p) {
    if (p > 0) __syncthreads();  // drains stage(p); prior reads already consumed
    if (p < 15) {                // async prefetch pass p+1 into other buffer
      const unsigned short* gp = gbase + (size_t)(p + 1) * 64 * 8;
      unsigned short* lb = Bb[(p + 1) & 1];
#pragma unroll
      for (int i = 0; i < 4; ++i)
        gll16(gp + (size_t)i * 16 * 8, &lb[i * 2048 + wid * 512]);
    }

    // consume: wave wid's region, lane-linear 16B reads (conflict-free)
    const unsigned short* Bp = Bb[p & 1];
    short8 bf[4];
#pragma unroll
    for (int ks = 0; ks < 4; ++ks)
      bf[ks] = *(const short8*)&Bp[wid * 2048 + ks * 512 + lane * 8];

    floatx4 acc[4];
#pragma unroll
    for (int rt = 0; rt < 4; ++rt) acc[rt] = (floatx4){0.f, 0.f, 0.f, 0.f};
#pragma unroll
    for (int ks = 0; ks < 4; ++ks)
#pragma unroll
      for (int rt = 0; rt < 4; ++rt)
        acc[rt] = __builtin_amdgcn_mfma_f32_16x16x32_bf16(af[rt][ks], bf[ks], acc[rt], 0, 0, 0);

    int col = p * 64 + wid * 16 + lc;
#pragma unroll
    for (int rt = 0; rt < 4; ++rt) {
      int own = b * 2 + (rt >> 1);
      bool isown = (col == own);
#pragma unroll
      for (int reg = 0; reg < 4; ++reg) {
        float l2 = fmaf(rsL[rt * 4 + reg], acc[rt][reg], c2);
        float e = exp2f(l2);
        if (isown) e = eolL[rt * 4 + reg];
        sAcc[rt * 4 + reg] += e;
      }
    }
  }

  // reduce over the 16 col-lanes (lc)
#pragma unroll
  for (int mask = 1; mask < 16; mask <<= 1)
#pragma unroll
    for (int j = 0; j < 16; ++j) sAcc[j] += __shfl_xor(sAcc[j], mask, 64);

  if (lc == 0)
#pragma unroll
    for (int rt = 0; rt < 4; ++rt)
#pragma unroll
      for (int reg = 0; reg < 4; ++reg)
        sPart[wid * 64 + rt * 16 + lg * 4 + reg] = sAcc[rt * 4 + reg];
  __syncthreads();

  if (t < 64) {
    float st = sPart[t] + sPart[64 + t] + sPart[128 + t] + sPart[192 + t];
    float lossr = M + logf(st) - olvg[b * 64 + t];
#pragma unroll
    for (int mask = 1; mask < 64; mask <<= 1) lossr += __shfl_xor(lossr, mask, 64);
    if (t == 0) atomicAdd(out, lossr * (1.0f / NROWS));
  }
}

// ---------------------------------------------------------------------------
extern "C" void kernel_launch(void* const* d_in, const int* in_sizes, int n_in,
                              void* d_out, int out_size, void* d_ws, size_t ws_size,
                              hipStream_t stream) {
  const float* emb = (const float*)d_in[0];
  const float* wp  = (const float*)d_in[1];
  const float* bp  = (const float*)d_in[2];

  char* ws = (char*)d_ws;
  unsigned short* centC = (unsigned short*)ws;          // 256 KB (chunked)
  float* rs2g = (float*)(ws + 262144);                  // 128 KB
  float* eolg = (float*)(ws + 262144 + 131072);         // 128 KB
  float* olvg = (float*)(ws + 262144 + 262144);         // 128 KB
  float* out = (float*)d_out;

  hipLaunchKernelGGL(k1, dim3(512), dim3(256), 0, stream,
                     emb, wp, bp, centC, rs2g, eolg, olvg, out);
  hipLaunchKernelGGL(k2, dim3(512), dim3(256), 0, stream,
                     emb, centC, rs2g, eolg, olvg, wp, bp, out);
}